// Round 7
// baseline (106.358 us; speedup 1.0000x reference)
//
#include <hip/hip_runtime.h>

constexpr int PIX   = 513 * 513;  // 263169 = 2056*128 + 1
constexpr int NTILE = 128;        // pixels per block

typedef short bf16x8 __attribute__((ext_vector_type(8)));
typedef float f32x4  __attribute__((ext_vector_type(4)));

// RNE f32 -> bf16 bits
__device__ __forceinline__ unsigned short f2bf(float f) {
    unsigned u = __builtin_bit_cast(unsigned, f);
    u += 0x7fffu + ((u >> 16) & 1u);
    return (unsigned short)(u >> 16);
}
__device__ __forceinline__ unsigned pack2(float a, float b) {
    return (unsigned)f2bf(a) | ((unsigned)f2bf(b) << 16);
}

// C[128 x P] = Wbig[128 x 128] * X[128 x P] + bias
//   X rows 0..63 = inputs_over, rows 64..127 = inputs_under
//   Wbig = [[w+, w-], [w-, w+]] ; C rows 0..63 -> out_over, 64..127 -> out_under
__global__ __launch_bounds__(256, 4) void mfma_bounds_kernel(
    const float* __restrict__ under,
    const float* __restrict__ over,
    const float* __restrict__ W,
    const float* __restrict__ bias,
    float* __restrict__ out_under,
    float* __restrict__ out_over)
{
    __shared__ alignas(16) unsigned short Xt[NTILE * 128];  // bf16 [px][k], 32 KB, swizzled

    const int t = threadIdx.x;
    const int pxbase = blockIdx.x * NTILE;

    if (pxbase + NTILE > PIX) {
        // ---- tail block (1 pixel): scalar f32 path ----
        if (t < 128) {
            const int m = t;
            const int o = m & 63;
            const float* prim = (m < 64) ? over  : under;
            const float* sec  = (m < 64) ? under : over;
            for (int p = pxbase; p < PIX; ++p) {
                float acc = bias[o];
                for (int i = 0; i < 64; ++i) {
                    const float w = W[o * 64 + i];
                    acc += fmaxf(w, 0.f) * prim[(size_t)i * PIX + p]
                         + fminf(w, 0.f) * sec [(size_t)i * PIX + p];
                }
                if (m < 64) out_over [(size_t)m        * PIX + p] = acc;
                else        out_under[(size_t)(m - 64) * PIX + p] = acc;
            }
        }
        return;
    }

    // ---- stage X tile: Xt[px][k] bf16, swizzle byte ^= (px&7)<<4, b128 writes ----
    {
        const int px    = t & 127;
        const int khalf = t >> 7;             // 0: k=0..63 (over), 1: k=64..127 (under)
        const float* src = khalf ? under : over;
        const size_t p  = (size_t)pxbase + px;
        const int xw    = (px & 7) << 4;
        #pragma unroll
        for (int seg = 0; seg < 8; ++seg) {   // 8 k-rows per iteration
            float v0 = src[(size_t)(seg * 8 + 0) * PIX + p];
            float v1 = src[(size_t)(seg * 8 + 1) * PIX + p];
            float v2 = src[(size_t)(seg * 8 + 2) * PIX + p];
            float v3 = src[(size_t)(seg * 8 + 3) * PIX + p];
            float v4 = src[(size_t)(seg * 8 + 4) * PIX + p];
            float v5 = src[(size_t)(seg * 8 + 5) * PIX + p];
            float v6 = src[(size_t)(seg * 8 + 6) * PIX + p];
            float v7 = src[(size_t)(seg * 8 + 7) * PIX + p];
            int4 pk;
            pk.x = (int)pack2(v0, v1);
            pk.y = (int)pack2(v2, v3);
            pk.z = (int)pack2(v4, v5);
            pk.w = (int)pack2(v6, v7);
            const int off = px * 256 + ((khalf * 128 + seg * 16) ^ xw);
            *(int4*)((char*)Xt + off) = pk;
        }
    }

    // ---- A fragments + bias straight from global (W is 16 KB, L1/L2-hot) ----
    const int wv   = t >> 6;
    const int lane = t & 63;
    const int lrow = lane & 15;
    const int lg   = lane >> 4;
    const int m0   = wv * 32;

    bf16x8 A[2][4];
    #pragma unroll
    for (int mt = 0; mt < 2; ++mt) {
        const int m = m0 + mt * 16 + lrow;
        const float* wr = W + (m & 63) * 64;
        #pragma unroll
        for (int ks = 0; ks < 4; ++ks) {
            const int kbase = ks * 32 + lg * 8;       // 8-aligned, never straddles 64
            const bool same = ((kbase < 64) == (m < 64));
            const float4 wa = *(const float4*)(wr + (kbase & 63));
            const float4 wb = *(const float4*)(wr + (kbase & 63) + 4);
            bf16x8 f;
            f[0] = (short)f2bf(same ? fmaxf(wa.x, 0.f) : fminf(wa.x, 0.f));
            f[1] = (short)f2bf(same ? fmaxf(wa.y, 0.f) : fminf(wa.y, 0.f));
            f[2] = (short)f2bf(same ? fmaxf(wa.z, 0.f) : fminf(wa.z, 0.f));
            f[3] = (short)f2bf(same ? fmaxf(wa.w, 0.f) : fminf(wa.w, 0.f));
            f[4] = (short)f2bf(same ? fmaxf(wb.x, 0.f) : fminf(wb.x, 0.f));
            f[5] = (short)f2bf(same ? fmaxf(wb.y, 0.f) : fminf(wb.y, 0.f));
            f[6] = (short)f2bf(same ? fmaxf(wb.z, 0.f) : fminf(wb.z, 0.f));
            f[7] = (short)f2bf(same ? fmaxf(wb.w, 0.f) : fminf(wb.w, 0.f));
            A[mt][ks] = f;
        }
    }

    float bb[2][4];
    #pragma unroll
    for (int mt = 0; mt < 2; ++mt)
        #pragma unroll
        for (int r = 0; r < 4; ++r)
            bb[mt][r] = bias[(m0 + mt * 16 + lg * 4 + r) & 63];

    __syncthreads();

    // prow = nt*16 + lrow, and (prow & 7) == (lrow & 7) since 16 | nt*16
    const int xwr = (lrow & 7) << 4;

    // ---- compute in two nt-halves of 4 (keeps acc at 32 VGPRs) ----
    #pragma unroll
    for (int h = 0; h < 2; ++h) {
        f32x4 acc[2][4];
        #pragma unroll
        for (int mt = 0; mt < 2; ++mt)
            #pragma unroll
            for (int n4 = 0; n4 < 4; ++n4) {
                f32x4 v = {bb[mt][0], bb[mt][1], bb[mt][2], bb[mt][3]};
                acc[mt][n4] = v;
            }

        #pragma unroll
        for (int n4 = 0; n4 < 4; ++n4) {
            const int nt   = h * 4 + n4;
            const int prow = nt * 16 + lrow;
            bf16x8 Bf[4];
            #pragma unroll
            for (int ks = 0; ks < 4; ++ks) {
                const int ch = ks * 4 + lg;
                Bf[ks] = *(const bf16x8*)((const char*)Xt +
                           prow * 256 + ((ch * 16) ^ xwr));
            }
            #pragma unroll
            for (int mt = 0; mt < 2; ++mt)
                #pragma unroll
                for (int ks = 0; ks < 4; ++ks)
                    acc[mt][n4] = __builtin_amdgcn_mfma_f32_16x16x32_bf16(
                        A[mt][ks], Bf[ks], acc[mt][n4], 0, 0, 0);
        }

        // ---- store this half: C[m][p], col = lane&15, row = lg*4 + r ----
        #pragma unroll
        for (int mt = 0; mt < 2; ++mt)
            #pragma unroll
            for (int r = 0; r < 4; ++r) {
                const int m = m0 + mt * 16 + lg * 4 + r;
                float* base = (m < 64) ? (out_over  + (size_t)m        * PIX)
                                       : (out_under + (size_t)(m - 64) * PIX);
                #pragma unroll
                for (int n4 = 0; n4 < 4; ++n4)
                    __builtin_nontemporal_store(acc[mt][n4][r],
                        base + pxbase + (h * 4 + n4) * 16 + lrow);
            }
    }
}

extern "C" void kernel_launch(void* const* d_in, const int* in_sizes, int n_in,
                              void* d_out, int out_size, void* d_ws, size_t ws_size,
                              hipStream_t stream) {
    const float* under = (const float*)d_in[0];
    const float* over  = (const float*)d_in[1];
    const float* W     = (const float*)d_in[2];
    const float* bias  = (const float*)d_in[3];
    float* out_under = (float*)d_out;
    float* out_over  = out_under + (size_t)64 * PIX;

    const int blocks = (PIX + NTILE - 1) / NTILE;  // 2057
    mfma_bounds_kernel<<<blocks, 256, 0, stream>>>(under, over, W, bias,
                                                   out_under, out_over);
}

// Round 8
// 80.858 us; speedup vs baseline: 1.3154x; 1.3154x over previous
//
#include <hip/hip_runtime.h>

constexpr int PIX   = 513 * 513;  // 263169 = 2056*128 + 1
constexpr int NTILE = 128;        // pixels per block

typedef short bf16x8 __attribute__((ext_vector_type(8)));
typedef float f32x4  __attribute__((ext_vector_type(4)));

// Precomputed Wbig = [[w+, w-], [w-, w+]] as bf16 bits, natural [m][k] layout.
__device__ unsigned short g_Wbig[128 * 128];  // 32 KB

// RNE f32 -> bf16 bits
__device__ __forceinline__ unsigned short f2bf(float f) {
    unsigned u = __builtin_bit_cast(unsigned, f);
    u += 0x7fffu + ((u >> 16) & 1u);
    return (unsigned short)(u >> 16);
}
__device__ __forceinline__ unsigned pack2(float a, float b) {
    return (unsigned)f2bf(a) | ((unsigned)f2bf(b) << 16);
}

__global__ __launch_bounds__(256) void prep_kernel(const float* __restrict__ W) {
    const int idx = blockIdx.x * 256 + threadIdx.x;   // 64 blocks -> 16384
    const int m = idx >> 7, k = idx & 127;
    const float w = W[(m & 63) * 64 + (k & 63)];
    const bool same = ((m < 64) == (k < 64));
    g_Wbig[idx] = f2bf(same ? fmaxf(w, 0.f) : fminf(w, 0.f));
}

// C[128 x P] = Wbig[128 x 128] * X[128 x P] + bias
//   X rows 0..63 = inputs_over, rows 64..127 = inputs_under
//   C rows 0..63 -> out_over, 64..127 -> out_under
__global__ __launch_bounds__(512, 4) void mfma_bounds_kernel(
    const float* __restrict__ under,
    const float* __restrict__ over,
    const float* __restrict__ W,
    const float* __restrict__ bias,
    float* __restrict__ out_under,
    float* __restrict__ out_over)
{
    __shared__ alignas(16) unsigned short Xt[NTILE * 128];  // bf16 [px][k], 32 KB, swizzled

    const int t = threadIdx.x;
    const int pxbase = blockIdx.x * NTILE;

    if (pxbase + NTILE > PIX) {
        // ---- tail block (1 pixel): scalar f32 path ----
        if (t < 128) {
            const int m = t;
            const int o = m & 63;
            const float* prim = (m < 64) ? over  : under;
            const float* sec  = (m < 64) ? under : over;
            for (int p = pxbase; p < PIX; ++p) {
                float acc = bias[o];
                for (int i = 0; i < 64; ++i) {
                    const float w = W[o * 64 + i];
                    acc += fmaxf(w, 0.f) * prim[(size_t)i * PIX + p]
                         + fminf(w, 0.f) * sec [(size_t)i * PIX + p];
                }
                if (m < 64) out_over [(size_t)m        * PIX + p] = acc;
                else        out_under[(size_t)(m - 64) * PIX + p] = acc;
            }
        }
        return;
    }

    // ---- stage X tile: Xt[px][k] bf16, swizzle byte ^= (px&7)<<4, b128 writes ----
    // 512 threads: px = t&127, kq = t>>7 owns k-rows [kq*32, kq*32+32)
    {
        const int px = t & 127;
        const int kq = t >> 7;                    // 0..3
        const float* src = (kq < 2) ? over : under;
        const int rbase = (kq & 1) * 32;          // row within src (kq<2: 0/32; else 0/32)
        const size_t p = (size_t)pxbase + px;
        const int xw = (px & 7) << 4;
        #pragma unroll
        for (int j = 0; j < 4; ++j) {             // 8 k-rows per b128 write
            const int r0 = rbase + j * 8;
            float v0 = src[(size_t)(r0 + 0) * PIX + p];
            float v1 = src[(size_t)(r0 + 1) * PIX + p];
            float v2 = src[(size_t)(r0 + 2) * PIX + p];
            float v3 = src[(size_t)(r0 + 3) * PIX + p];
            float v4 = src[(size_t)(r0 + 4) * PIX + p];
            float v5 = src[(size_t)(r0 + 5) * PIX + p];
            float v6 = src[(size_t)(r0 + 6) * PIX + p];
            float v7 = src[(size_t)(r0 + 7) * PIX + p];
            int4 pk;
            pk.x = (int)pack2(v0, v1);
            pk.y = (int)pack2(v2, v3);
            pk.z = (int)pack2(v4, v5);
            pk.w = (int)pack2(v6, v7);
            const int off = px * 256 + ((kq * 64 + j * 16) ^ xw);
            *(int4*)((char*)Xt + off) = pk;
        }
    }

    // ---- A fragments straight from global Wbig (bf16, L1/L2-hot) ----
    const int wv   = t >> 6;        // 8 waves, wave owns C rows [wv*16, wv*16+16)
    const int lane = t & 63;
    const int lrow = lane & 15;
    const int lg   = lane >> 4;
    const int m0   = wv * 16;

    bf16x8 A[4];
    #pragma unroll
    for (int ks = 0; ks < 4; ++ks)
        A[ks] = *(const bf16x8*)&g_Wbig[(m0 + lrow) * 128 + ks * 32 + lg * 8];

    float bb[4];
    #pragma unroll
    for (int r = 0; r < 4; ++r)
        bb[r] = bias[(m0 + lg * 4 + r) & 63];

    __syncthreads();

    // prow = nt*16 + lrow  =>  (prow & 7) == (lrow & 7)
    const int xwr = (lrow & 7) << 4;

    f32x4 acc[8];
    #pragma unroll
    for (int nt = 0; nt < 8; ++nt) {
        f32x4 v = {bb[0], bb[1], bb[2], bb[3]};
        acc[nt] = v;
    }

    #pragma unroll
    for (int nt = 0; nt < 8; ++nt) {
        const int prow = nt * 16 + lrow;
        bf16x8 Bf[4];
        #pragma unroll
        for (int ks = 0; ks < 4; ++ks) {
            const int ch = ks * 4 + lg;
            Bf[ks] = *(const bf16x8*)((const char*)Xt + prow * 256 + ((ch * 16) ^ xwr));
        }
        #pragma unroll
        for (int ks = 0; ks < 4; ++ks)
            acc[nt] = __builtin_amdgcn_mfma_f32_16x16x32_bf16(A[ks], Bf[ks], acc[nt], 0, 0, 0);
    }

    // ---- store: C[m][p], col = lane&15, row = lg*4 + r (verified layout) ----
    #pragma unroll
    for (int r = 0; r < 4; ++r) {
        const int m = m0 + lg * 4 + r;
        float* base = (m < 64) ? (out_over  + (size_t)m        * PIX)
                               : (out_under + (size_t)(m - 64) * PIX);
        #pragma unroll
        for (int nt = 0; nt < 8; ++nt)
            __builtin_nontemporal_store(acc[nt][r], base + pxbase + nt * 16 + lrow);
    }
}

extern "C" void kernel_launch(void* const* d_in, const int* in_sizes, int n_in,
                              void* d_out, int out_size, void* d_ws, size_t ws_size,
                              hipStream_t stream) {
    const float* under = (const float*)d_in[0];
    const float* over  = (const float*)d_in[1];
    const float* W     = (const float*)d_in[2];
    const float* bias  = (const float*)d_in[3];
    float* out_under = (float*)d_out;
    float* out_over  = out_under + (size_t)64 * PIX;

    prep_kernel<<<64, 256, 0, stream>>>(W);

    const int blocks = (PIX + NTILE - 1) / NTILE;  // 2057
    mfma_bounds_kernel<<<blocks, 512, 0, stream>>>(under, over, W, bias,
                                                   out_under, out_over);
}